// Round 9
// baseline (295.830 us; speedup 1.0000x reference)
//
#include <hip/hip_runtime.h>
#include <stdint.h>

#define B_ 128
#define T_ 1000
#define H_ 512
#define PH 8          // steps per phase
#define NPHASE 125    // T_/PH

typedef float vfloat4 __attribute__((ext_vector_type(4)));

// DPP-based add of a lane-shifted copy. row_shr:N = 0x110|N, row_bcast:15/31 = 0x142/0x143.
template <int CTRL>
__device__ __forceinline__ float dpp_add(float x) {
    int moved = __builtin_amdgcn_update_dpp(0, __float_as_int(x), CTRL, 0xf, 0xf, true);
    return x + __int_as_float(moved);
}

// Wave64 sum of 2 values simultaneously. Totals valid in lane 63.
__device__ __forceinline__ void wave_reduce2(float& p0, float& p1) {
    p0 = dpp_add<0x111>(p0); p1 = dpp_add<0x111>(p1);
    p0 = dpp_add<0x112>(p0); p1 = dpp_add<0x112>(p1);
    p0 = dpp_add<0x114>(p0); p1 = dpp_add<0x114>(p1);
    p0 = dpp_add<0x118>(p0); p1 = dpp_add<0x118>(p1);
    p0 = dpp_add<0x142>(p0); p1 = dpp_add<0x142>(p1);
    p0 = dpp_add<0x143>(p0); p1 = dpp_add<0x143>(p1);
}

// Wave64 sum of 1 value. Valid in lane 63.
__device__ __forceinline__ float wave_reduce1(float p) {
    p = dpp_add<0x111>(p); p = dpp_add<0x112>(p); p = dpp_add<0x114>(p);
    p = dpp_add<0x118>(p); p = dpp_add<0x142>(p); p = dpp_add<0x143>(p);
    return p;
}

// tanh(x) = 1 - 2/(e^{2x}+1) via hardware exp2 + rcp.
__device__ __forceinline__ float fast_tanh(float x) {
    float E = __builtin_amdgcn_exp2f(x * 2.885390081777927f);
    float r = __builtin_amdgcn_rcpf(E + 1.0f);
    return __builtin_fmaf(-2.0f, r, 1.0f);
}

__global__ __launch_bounds__(128, 1) void lowrank_rnn_kernel(
    const float* __restrict__ input,   // (B,T,3)
    const float* __restrict__ noise,   // (B,T,H)
    const float* __restrict__ wi,      // (3,H)
    const float* __restrict__ si,      // (3,)
    const float* __restrict__ m,       // (H,2)
    const float* __restrict__ n,       // (H,2)
    const float* __restrict__ wo,      // (H,1)
    const float* __restrict__ so,      // (1,)
    const float* __restrict__ h0,      // (H,)
    float* __restrict__ out)           // [output (B,T,1) | traj (B,T+1,H)]
{
    const int b    = blockIdx.x;   // one batch element per block (2 waves)
    const int tid  = threadIdx.x;
    const int wid  = tid >> 6;     // 0 = consumer (serial chain), 1 = producer
    const int lane = tid & 63;
    const int j0   = lane * 8;     // hidden units j0..j0+7 owned by this lane

    // Rings: [half][row-in-phase][plane][lane] — 16B/lane stride, conflict-free.
    __shared__ __align__(16) vfloat4 ub[2][PH][2][64];   // 32 KB: u = 0.05z + x·wS
    __shared__ __align__(16) vfloat4 rb[2][PH][2][64];   // 32 KB: r = tanh(h_t)
    __shared__ __align__(16) vfloat4 hb[2][PH][2][64];   // 32 KB: h_{t+1}
    __shared__ __align__(16) vfloat4 rfin[2][64];        //  2 KB: final r
    __shared__ float os[T_ + 1];                         //  4 KB
    __shared__ int   flags[2];                           // [0]=vprod, [1]=vcons

    if (tid == 0) { flags[0] = 0; flags[1] = 0; }
    __syncthreads();   // only full barrier in the kernel
    volatile int* vprod = &flags[0];
    volatile int* vcons = &flags[1];

    if (wid == 1) {
        // ========== PRODUCER: z loads, u precompute, os dot, traj stores ==========
        float wS0[8], wS1[8], wS2[8], wof[8];
        {
            const float so0 = so[0];
            #pragma unroll
            for (int i = 0; i < 3; ++i) {
                float s = 0.2f * si[i];
                float* dst = (i == 0) ? wS0 : (i == 1) ? wS1 : wS2;
                #pragma unroll
                for (int q = 0; q < 2; ++q) {
                    vfloat4 vw = *(const vfloat4*)(wi + i * H_ + j0 + 4 * q);
                    dst[4*q] = vw.x * s; dst[4*q+1] = vw.y * s;
                    dst[4*q+2] = vw.z * s; dst[4*q+3] = vw.w * s;
                }
            }
            #pragma unroll
            for (int q = 0; q < 2; ++q) {
                vfloat4 vw = *(const vfloat4*)(wo + j0 + 4 * q);
                wof[4*q] = vw.x * so0; wof[4*q+1] = vw.y * so0;
                wof[4*q+2] = vw.z * so0; wof[4*q+3] = vw.w * so0;
            }
        }
        const float* zb = noise + (size_t)b * T_ * H_ + j0;
        const float* xb = input + (size_t)b * T_ * 3;    // wave-uniform
        float* trajBase = out + (size_t)B_ * T_ + (size_t)b * (T_ + 1) * H_;

        {   // trajectories[:,0,:] = h0 (one-time)
            vfloat4 a = *(const vfloat4*)(h0 + j0);
            vfloat4 c = *(const vfloat4*)(h0 + j0 + 4);
            *(vfloat4*)(trajBase + j0)     = a;
            *(vfloat4*)(trajBase + j0 + 4) = c;
        }

        // os dot + traj stores for a finished phase pp (requires vcons >= pp+1).
        auto emit_phase = [&](int pp) {
            const int hf = pp & 1;
            #pragma unroll
            for (int s = 0; s < PH; ++s) {
                const int t = pp * PH + s;
                vfloat4 rl = rb[hf][s][0][lane];
                vfloat4 rh = rb[hf][s][1][lane];
                float p2 = rl.x * wof[0];
                p2 = __builtin_fmaf(rl.y, wof[1], p2);
                p2 = __builtin_fmaf(rl.z, wof[2], p2);
                p2 = __builtin_fmaf(rl.w, wof[3], p2);
                p2 = __builtin_fmaf(rh.x, wof[4], p2);
                p2 = __builtin_fmaf(rh.y, wof[5], p2);
                p2 = __builtin_fmaf(rh.z, wof[6], p2);
                p2 = __builtin_fmaf(rh.w, wof[7], p2);
                p2 = wave_reduce1(p2);
                if (lane == 63) os[t] = p2;      // out[t-1]
                vfloat4 hl = hb[hf][s][0][lane];
                vfloat4 hh = hb[hf][s][1][lane];
                float* tr = trajBase + (size_t)(t + 1) * H_ + j0;
                *(vfloat4*)tr       = hl;
                *(vfloat4*)(tr + 4) = hh;
            }
        };

        for (int q = 0; q < NPHASE; ++q) {
            if (q >= 2) {                        // ring space + phase q-2 finished
                while (*vcons < q - 1) {}
                asm volatile("" ::: "memory");
            }
            // Issue z loads for phase q first; emit_phase below hides their latency.
            vfloat4 zl[PH], zh[PH];
            #pragma unroll
            for (int s = 0; s < PH; ++s) {
                const float* g = zb + (size_t)(q * PH + s) * H_;
                zl[s] = *(const vfloat4*)g;
                zh[s] = *(const vfloat4*)(g + 4);
            }
            if (q >= 2) emit_phase(q - 2);
            const int half = q & 1;
            #pragma unroll
            for (int s = 0; s < PH; ++s) {
                const int t = q * PH + s;
                float x0 = xb[3*t], x1 = xb[3*t+1], x2 = xb[3*t+2];
                float zz[8] = {zl[s].x, zl[s].y, zl[s].z, zl[s].w,
                               zh[s].x, zh[s].y, zh[s].z, zh[s].w};
                float u[8];
                #pragma unroll
                for (int k = 0; k < 8; ++k) {
                    float xw = __builtin_fmaf(x0, wS0[k],
                               __builtin_fmaf(x1, wS1[k], x2 * wS2[k]));
                    u[k] = __builtin_fmaf(zz[k], 0.05f, xw);
                }
                vfloat4 ulo = {u[0], u[1], u[2], u[3]};
                vfloat4 uhi = {u[4], u[5], u[6], u[7]};
                ub[half][s][0][lane] = ulo;
                ub[half][s][1][lane] = uhi;
            }
            asm volatile("s_waitcnt lgkmcnt(0)" ::: "memory");
            if (lane == 0) *vprod = q + 1;   // also certifies os/traj(q-2) done
        }
        // Tail: phases 123, 124, then final output element.
        while (*vcons < NPHASE) {}            // consumer finished phase 124
        asm volatile("" ::: "memory");
        emit_phase(NPHASE - 2);
        emit_phase(NPHASE - 1);
        while (*vcons < NPHASE + 1) {}        // final r available
        asm volatile("" ::: "memory");
        {
            vfloat4 rl = rfin[0][lane], rh = rfin[1][lane];
            float p2 = rl.x * wof[0];
            p2 = __builtin_fmaf(rl.y, wof[1], p2);
            p2 = __builtin_fmaf(rl.z, wof[2], p2);
            p2 = __builtin_fmaf(rl.w, wof[3], p2);
            p2 = __builtin_fmaf(rh.x, wof[4], p2);
            p2 = __builtin_fmaf(rh.y, wof[5], p2);
            p2 = __builtin_fmaf(rh.z, wof[6], p2);
            p2 = __builtin_fmaf(rh.w, wof[7], p2);
            p2 = wave_reduce1(p2);
            if (lane == 63) os[T_] = p2;
        }
        asm volatile("s_waitcnt lgkmcnt(0)" ::: "memory");
        float* outp = out + (size_t)b * T_;
        for (int idx = lane; idx < T_; idx += 64)
            outp[idx] = os[idx + 1];
    } else {
        // ========== CONSUMER: the serial chain. No global ops in the loop. ==========
        float h[8], n0[8], n1[8], m0S[8], m1S[8];
        {
            const float* nb = n + 2 * j0;
            const float* mb = m + 2 * j0;
            #pragma unroll
            for (int q = 0; q < 4; ++q) {
                vfloat4 vn = *(const vfloat4*)(nb + 4 * q);
                n0[2*q] = vn.x; n1[2*q] = vn.y; n0[2*q+1] = vn.z; n1[2*q+1] = vn.w;
                vfloat4 vm = *(const vfloat4*)(mb + 4 * q);
                m0S[2*q] = 0.2f * vm.x;   m1S[2*q] = 0.2f * vm.y;
                m0S[2*q+1] = 0.2f * vm.z; m1S[2*q+1] = 0.2f * vm.w;
            }
            #pragma unroll
            for (int q = 0; q < 2; ++q) {
                vfloat4 vh = *(const vfloat4*)(h0 + j0 + 4 * q);
                h[4*q] = vh.x; h[4*q+1] = vh.y; h[4*q+2] = vh.z; h[4*q+3] = vh.w;
            }
        }

        for (int p = 0; p < NPHASE; ++p) {
            while (*vprod < p + 1) {}        // u ready AND ring slot p&1 free
            asm volatile("" ::: "memory");
            const int half = p & 1;
            vfloat4 cul = ub[half][0][0][lane];
            vfloat4 cuh = ub[half][0][1][lane];
            #pragma unroll
            for (int s = 0; s < PH; ++s) {
                vfloat4 nul, nuh;
                if (s < PH - 1) {            // prefetch next step's u
                    nul = ub[half][s+1][0][lane];
                    nuh = ub[half][s+1][1][lane];
                }
                float r[8];
                #pragma unroll
                for (int k = 0; k < 8; ++k) r[k] = fast_tanh(h[k]);

                float p0 = r[0] * n0[0], p1 = r[0] * n1[0];
                #pragma unroll
                for (int k = 1; k < 8; ++k) {
                    p0 = __builtin_fmaf(r[k], n0[k], p0);
                    p1 = __builtin_fmaf(r[k], n1[k], p1);
                }
                wave_reduce2(p0, p1);

                float uu[8] = {cul.x, cul.y, cul.z, cul.w, cuh.x, cuh.y, cuh.z, cuh.w};
                float base[8];
                #pragma unroll
                for (int k = 0; k < 8; ++k)
                    base[k] = __builtin_fmaf(h[k], 0.8f, uu[k]);

                float a0 = __int_as_float(__builtin_amdgcn_readlane(__float_as_int(p0), 63));
                float a1 = __int_as_float(__builtin_amdgcn_readlane(__float_as_int(p1), 63));

                #pragma unroll
                for (int k = 0; k < 8; ++k)
                    h[k] = __builtin_fmaf(a0, m0S[k], __builtin_fmaf(a1, m1S[k], base[k]));

                // Ship r (for os) and h (for traj) to the producer.
                vfloat4 rlo = {r[0], r[1], r[2], r[3]};
                vfloat4 rhi = {r[4], r[5], r[6], r[7]};
                rb[half][s][0][lane] = rlo;
                rb[half][s][1][lane] = rhi;
                vfloat4 hlo = {h[0], h[1], h[2], h[3]};
                vfloat4 hhi = {h[4], h[5], h[6], h[7]};
                hb[half][s][0][lane] = hlo;
                hb[half][s][1][lane] = hhi;

                cul = nul; cuh = nuh;
            }
            asm volatile("s_waitcnt lgkmcnt(0)" ::: "memory");  // rings visible
            if (lane == 0) *vcons = p + 1;
        }
        // Final r = tanh(h_T) for out[T-1].
        while (*vprod < NPHASE) {}           // producer read slot (122) done
        asm volatile("" ::: "memory");
        float r[8];
        #pragma unroll
        for (int k = 0; k < 8; ++k) r[k] = fast_tanh(h[k]);
        vfloat4 rlo = {r[0], r[1], r[2], r[3]};
        vfloat4 rhi = {r[4], r[5], r[6], r[7]};
        rfin[0][lane] = rlo;
        rfin[1][lane] = rhi;
        asm volatile("s_waitcnt lgkmcnt(0)" ::: "memory");
        if (lane == 0) *vcons = NPHASE + 1;
    }
}

extern "C" void kernel_launch(void* const* d_in, const int* in_sizes, int n_in,
                              void* d_out, int out_size, void* d_ws, size_t ws_size,
                              hipStream_t stream) {
    const float* input = (const float*)d_in[0];
    const float* noise = (const float*)d_in[1];
    const float* wi    = (const float*)d_in[2];
    const float* si    = (const float*)d_in[3];
    const float* m     = (const float*)d_in[4];
    const float* n     = (const float*)d_in[5];
    const float* wo    = (const float*)d_in[6];
    const float* so    = (const float*)d_in[7];
    const float* h0    = (const float*)d_in[8];
    float* out = (float*)d_out;

    hipLaunchKernelGGL(lowrank_rnn_kernel, dim3(B_), dim3(128), 0, stream,
                       input, noise, wi, si, m, n, wo, so, h0, out);
}